// Round 10
// baseline (1363.874 us; speedup 1.0000x reference)
//
#include <hip/hip_runtime.h>
#include <hip/hip_fp16.h>
#include <math.h>

#define NPTS 16384
#define NB 16
#define BNTOT (NB * NPTS)
#define NP 16

typedef _Float16 f16;
typedef __attribute__((ext_vector_type(8))) _Float16 f16x8;
typedef __attribute__((ext_vector_type(4))) float f32x4;

struct alignas(8) F16x4 { f16 v[4]; };

// XCD-aware block swizzle (proved: FETCH 131->33MB on conv2). Bijective when
// total blocks % 8 == 0; keeps all x-tiles of one y-slab on one XCD.
__device__ inline void xcd_swz(int& bx, int& by)
{
    const int flatb = blockIdx.y * gridDim.x + blockIdx.x;
    const int slot = flatb >> 3, xcd = flatb & 7;
    bx = slot % gridDim.x;
    by = (slot / gridDim.x) * 8 + xcd;
}

// ---------------------------------------------------------------------------
// fp32 VALU conv (conv1..conv3), PT=4 (round-8 structure: per-output-element
// FMA chain over ascending c is BIT-IDENTICAL -> sort indices preserved).
// Changes vs round 8: XCD swizzle; staging o-fastest (bank-conflict-free LDS
// writes: banks = o%32, 2-way); launch_bounds(256,3).
// ---------------------------------------------------------------------------
template<int CIN, int OT, int MODE, bool STATS>
__global__ __launch_bounds__(256, 3) void conv_k(
    const float* __restrict__ X, const float* __restrict__ W,
    const float* __restrict__ insc, const float* __restrict__ insh,
    float* __restrict__ Y, float* __restrict__ ssum, float* __restrict__ ssq,
    int COUT)
{
    constexpr int PT = 4;
    constexpr int NT = 256 * PT;               // 1024 points per block
    constexpr int CC = (CIN < 128) ? CIN : 128;
    __shared__ __align__(16) float Ws[CC][OT];
    __shared__ float lsum[OT];
    __shared__ float lsq[OT];

    int bx, by;
    xcd_swz(bx, by);
    const int tid = threadIdx.x;
    const int b = (by * NT) / NPTS;
    const int n = (by * NT) % NPTS + tid * PT;
    const int obase = bx * OT;

    if (STATS) {
        for (int i = tid; i < OT; i += 256) { lsum[i] = 0.f; lsq[i] = 0.f; }
    }

    float acc[OT][PT];
#pragma unroll
    for (int o = 0; o < OT; ++o)
#pragma unroll
        for (int p = 0; p < PT; ++p) acc[o][p] = 0.f;

    const float* Xb = X + (size_t)b * CIN * NPTS;

    for (int c0 = 0; c0 < CIN; c0 += CC) {
        // o-fastest staging: LDS write banks = o%32 (2 lanes/bank, free);
        // W reads strided by CIN but W <= 32KB -> L1/L2-resident.
        for (int i = tid; i < CC * OT; i += 256) {
            int o = i % OT, c = i / OT;
            int oo = obase + o;
            Ws[c][o] = (oo < COUT) ? W[(size_t)oo * CIN + (c0 + c)] : 0.f;
        }
        __syncthreads();
#pragma unroll 2
        for (int c = 0; c < CC; ++c) {
            const int cx = c0 + c;
            float xv[PT];
            float4 t = *(const float4*)(Xb + (size_t)cx * NPTS + n);
            xv[0] = t.x; xv[1] = t.y; xv[2] = t.z; xv[3] = t.w;
            if (MODE == 1) {
                float s = insc[cx], h = insh[cx];
#pragma unroll
                for (int p = 0; p < PT; ++p)
                    xv[p] = fmaxf(fmaf(xv[p], s, h), 0.f);
            }
            const float4* wrow = (const float4*)(&Ws[c][0]);
#pragma unroll
            for (int o4 = 0; o4 < OT / 4; ++o4) {
                float4 w = wrow[o4];
#pragma unroll
                for (int p = 0; p < PT; ++p) {
                    acc[o4 * 4 + 0][p] = fmaf(w.x, xv[p], acc[o4 * 4 + 0][p]);
                    acc[o4 * 4 + 1][p] = fmaf(w.y, xv[p], acc[o4 * 4 + 1][p]);
                    acc[o4 * 4 + 2][p] = fmaf(w.z, xv[p], acc[o4 * 4 + 2][p]);
                    acc[o4 * 4 + 3][p] = fmaf(w.w, xv[p], acc[o4 * 4 + 3][p]);
                }
            }
        }
        __syncthreads();
    }

#pragma unroll
    for (int o = 0; o < OT; ++o) {
        const int oo = obase + o;
        if (oo < COUT) {
            float v[PT];
#pragma unroll
            for (int p = 0; p < PT; ++p) v[p] = acc[o][p];
            *(float4*)(Y + ((size_t)b * COUT + oo) * NPTS + n) =
                make_float4(v[0], v[1], v[2], v[3]);
            if (STATS) {
                float s = (v[0] + v[1]) + (v[2] + v[3]);
                float q = fmaf(v[0], v[0], fmaf(v[1], v[1], fmaf(v[2], v[2], v[3] * v[3])));
#pragma unroll
                for (int d = 32; d >= 1; d >>= 1) {
                    s += __shfl_xor(s, d, 64);
                    q += __shfl_xor(q, d, 64);
                }
                if ((tid & 63) == 0) {
                    atomicAdd(&lsum[o], s);
                    atomicAdd(&lsq[o], q);
                }
            }
        }
    }
    if (STATS) {
        __syncthreads();
        for (int i = tid; i < OT; i += 256) {
            int oo = obase + i;
            if (oo < COUT) {
                atomicAdd(&ssum[oo], lsum[i]);
                atomicAdd(&ssq[oo], lsq[i]);
            }
        }
    }
}

// per-channel BN fold: scale = g/sqrt(var+eps), shift = be - mean*scale
__global__ void bnstats_k(const float* __restrict__ ssum, const float* __restrict__ ssq,
                          const float* __restrict__ g, const float* __restrict__ be,
                          float* __restrict__ scale, float* __restrict__ shift, int C)
{
    int c = blockIdx.x * blockDim.x + threadIdx.x;
    if (c >= C) return;
    const float inv = 1.0f / (float)BNTOT;
    float m = ssum[c] * inv;
    float var = fmaf(ssq[c], inv, -m * m);
    float sc = g[c] / sqrtf(var + 1e-5f);
    scale[c] = sc;
    shift[c] = fmaf(-m, sc, be[c]);
}

// SoftPool (UNCHANGED): stable 16-smallest per (b,k), then gather-dot.
__global__ __launch_bounds__(256) void softpool_k(
    const float* __restrict__ y3, const float* __restrict__ sc3,
    const float* __restrict__ sh3, const float* __restrict__ w9,
    const float* __restrict__ b9, float* __restrict__ vout)
{
    extern __shared__ float vals[];
    __shared__ int sidx[NP];
    __shared__ float wv[4];
    __shared__ int wi[4];
    __shared__ float ps[4];

    const int tid = threadIdx.x;
    const int b = blockIdx.x >> 5;
    const int k = blockIdx.x & 31;

    const float* src = y3 + ((size_t)b * 32 + k) * NPTS;
    const float sck = sc3[k], shk = sh3[k];
    for (int i = tid; i < NPTS; i += 256) vals[i] = fmaf(src[i], sck, shk);
    __syncthreads();

    for (int p = 0; p < NP; ++p) {
        float bv = INFINITY;
        int bi = 0x7fffffff;
        for (int i = tid; i < NPTS; i += 256) {
            float x = vals[i];
            if (x < bv) { bv = x; bi = i; }
        }
#pragma unroll
        for (int d = 32; d >= 1; d >>= 1) {
            float ov = __shfl_xor(bv, d, 64);
            int oi = __shfl_xor(bi, d, 64);
            if (ov < bv || (ov == bv && oi < bi)) { bv = ov; bi = oi; }
        }
        if ((tid & 63) == 0) { wv[tid >> 6] = bv; wi[tid >> 6] = bi; }
        __syncthreads();
        if (tid == 0) {
            for (int w = 1; w < 4; ++w)
                if (wv[w] < bv || (wv[w] == bv && wi[w] < bi)) { bv = wv[w]; bi = wi[w]; }
            sidx[p] = bi;
            vals[bi] = INFINITY;
        }
        __syncthreads();
    }

    float part = 0.f;
    for (int i = tid; i < 32 * NP; i += 256) {
        int c = i >> 4, p = i & 15;
        float h = fmaf(y3[((size_t)b * 32 + c) * NPTS + sidx[p]], sc3[c], sh3[c]);
        part += w9[c * NP + p] * h;
    }
#pragma unroll
    for (int d = 32; d >= 1; d >>= 1) part += __shfl_xor(part, d, 64);
    if ((tid & 63) == 0) ps[tid >> 6] = part;
    __syncthreads();
    if (tid == 0) vout[b * 32 + k] = ps[0] + ps[1] + ps[2] + ps[3] + b9[0];
}

// h1T[b][n][64] fp16 = relu(bn1(y1)), LDS transpose; S1b per-(b,c) sums.
__global__ __launch_bounds__(256) void transformT_k(
    const float* __restrict__ y1, const float* __restrict__ sc,
    const float* __restrict__ sh, f16* __restrict__ h1T, float* __restrict__ S1b)
{
    __shared__ float arr[64][65];
    __shared__ float s1loc[64];
    const int tid = threadIdx.x;
    const int b = blockIdx.x >> 8;
    const int n0 = (blockIdx.x & 255) * 64;
    if (tid < 64) s1loc[tid] = 0.f;

    const int c = tid >> 2, j4 = tid & 3;
    const float scv = sc[c], shv = sh[c];
    const float* src = y1 + ((size_t)b * 64 + c) * NPTS + n0 + j4 * 16;
    float ls = 0.f;
#pragma unroll
    for (int j = 0; j < 4; ++j) {
        float4 v = *(const float4*)(src + j * 4);
        float r0 = fmaxf(fmaf(v.x, scv, shv), 0.f);
        float r1 = fmaxf(fmaf(v.y, scv, shv), 0.f);
        float r2 = fmaxf(fmaf(v.z, scv, shv), 0.f);
        float r3 = fmaxf(fmaf(v.w, scv, shv), 0.f);
        arr[j4 * 16 + j * 4 + 0][c] = r0;
        arr[j4 * 16 + j * 4 + 1][c] = r1;
        arr[j4 * 16 + j * 4 + 2][c] = r2;
        arr[j4 * 16 + j * 4 + 3][c] = r3;
        ls += (r0 + r1) + (r2 + r3);
    }
    ls += __shfl_xor(ls, 1, 64);
    ls += __shfl_xor(ls, 2, 64);
    if (j4 == 0) atomicAdd(&s1loc[c], ls);
    __syncthreads();

    const int n = tid >> 2, cj = (tid & 3) * 16;
    f16x8 h0, h1v;
#pragma unroll
    for (int jj = 0; jj < 8; ++jj) h0[jj] = (f16)arr[n][cj + jj];
#pragma unroll
    for (int jj = 0; jj < 8; ++jj) h1v[jj] = (f16)arr[n][cj + 8 + jj];
    f16* dst = h1T + ((size_t)b * NPTS + n0 + n) * 64 + cj;
    *(f16x8*)(dst) = h0;
    *(f16x8*)(dst + 8) = h1v;

    if (tid < 64) atomicAdd(&S1b[b * 64 + tid], s1loc[tid]);
}

// MFMA SYRK (UNCHANGED): M[i][j] = sum_r H[r][i]*H[r][j] over h1T.
__global__ __launch_bounds__(256, 2) void msyrk_k(const f16* __restrict__ h1T,
                                                  float* __restrict__ M)
{
    __shared__ float Mlds[4][4096];
    const int tid = threadIdx.x;
    const int lane = tid & 63;
    const int llo = lane & 15, lhi = lane >> 4;
    const int wv = tid >> 6;
    const int gw = blockIdx.x * 4 + wv;
    constexpr int SPW = (BNTOT / 32) / 2048;

    f32x4 acc[4][4];
#pragma unroll
    for (int ti = 0; ti < 4; ++ti)
#pragma unroll
        for (int tj = 0; tj < 4; ++tj) acc[ti][tj] = (f32x4){0.f, 0.f, 0.f, 0.f};

#pragma unroll
    for (int s = 0; s < SPW; ++s) {
        const size_t r0 = (size_t)gw * (SPW * 32) + (size_t)s * 32 + 8 * lhi;
        const f16* base = h1T + r0 * 64 + llo;
        f16x8 f[4];
#pragma unroll
        for (int t = 0; t < 4; ++t)
#pragma unroll
            for (int i = 0; i < 8; ++i)
                f[t][i] = base[(size_t)i * 64 + t * 16];
#pragma unroll
        for (int ti = 0; ti < 4; ++ti)
#pragma unroll
            for (int tj = 0; tj < 4; ++tj)
                acc[ti][tj] = __builtin_amdgcn_mfma_f32_16x16x32_f16(
                    f[ti], f[tj], acc[ti][tj], 0, 0, 0);
    }

#pragma unroll
    for (int ti = 0; ti < 4; ++ti)
#pragma unroll
        for (int tj = 0; tj < 4; ++tj)
#pragma unroll
            for (int r = 0; r < 4; ++r)
                Mlds[wv][(ti * 16 + 4 * lhi + r) * 64 + tj * 16 + llo] = acc[ti][tj][r];
    __syncthreads();
    for (int i = tid; i < 4096; i += 256)
        atomicAdd(&M[i], (Mlds[0][i] + Mlds[1][i]) + (Mlds[2][i] + Mlds[3][i]));
}

// BN4 from input moments; emits per-(b,o) fused shift.
__global__ void bnstats45_k(const float* __restrict__ w4, const float* __restrict__ vv,
                            const float* __restrict__ S1b, const float* __restrict__ M,
                            const float* __restrict__ g, const float* __restrict__ be,
                            float* __restrict__ sc4, float* __restrict__ shift4b)
{
    __shared__ float vvL[512], sbL[1024], ML[4096];
    const int tid = threadIdx.x;
    for (int i = tid; i < 512; i += 512) vvL[i] = vv[i];
    for (int i = tid; i < 1024; i += 512) sbL[i] = S1b[i];
    for (int i = tid; i < 4096; i += 512) ML[i] = M[i];
    __syncthreads();
    const int o = tid;
    float wg[32], wh[64];
#pragma unroll
    for (int i = 0; i < 32; ++i) wg[i] = w4[o * 96 + i];
#pragma unroll
    for (int j = 0; j < 64; ++j) wh[j] = w4[o * 96 + 32 + j];
    float gbv[16];
    float sumy = 0.f, sumsq = 0.f;
#pragma unroll
    for (int b = 0; b < 16; ++b) {
        float gb = 0.f, hb = 0.f;
#pragma unroll
        for (int i = 0; i < 32; ++i) gb = fmaf(wg[i], vvL[b * 32 + i], gb);
#pragma unroll
        for (int j = 0; j < 64; ++j) hb = fmaf(wh[j], sbL[b * 64 + j], hb);
        gbv[b] = gb;
        sumy += (float)NPTS * gb + hb;
        sumsq += (float)NPTS * gb * gb + 2.f * gb * hb;
    }
    for (int j = 0; j < 64; ++j) {
        float t = 0.f;
#pragma unroll
        for (int j2 = 0; j2 < 64; ++j2) t = fmaf(ML[j * 64 + j2], wh[j2], t);
        sumsq = fmaf(wh[j], t, sumsq);
    }
    const float inv = 1.0f / (float)BNTOT;
    float m = sumy * inv;
    float var = fmaf(sumsq, inv, -m * m);
    float s = g[o] / sqrtf(var + 1e-5f);
    float sh4v = fmaf(-m, s, be[o]);
    sc4[o] = s;
#pragma unroll
    for (int b = 0; b < 16; ++b)
        shift4b[b * 512 + o] = fmaf(gbv[b], s, sh4v);
}

// fp32 -> fp16 weight conversion (optionally a column slice of src)
__global__ void wcvt_k(const float* __restrict__ src, f16* __restrict__ dst,
                       int rows, int cols, int srcStride, int srcOff)
{
    int i = blockIdx.x * 256 + threadIdx.x;
    if (i < rows * cols) {
        int r = i / cols, c = i % cols;
        dst[i] = (f16)src[(size_t)r * srcStride + srcOff + c];
    }
}

// ---------------------------------------------------------------------------
// LDS-tiled MFMA GEMM (round-7 structure + XCD swizzle). UNCHANGED.
// ---------------------------------------------------------------------------
#define GLOAD(KT, RA, RB)                                                       \
  {                                                                             \
    const int kb_ = (KT) * 64 + sj * 8;                                         \
    float4 is0, is1, ih0, ih1;                                                  \
    if (INAFF) {                                                                \
      is0 = *(const float4*)(insc + kb_); is1 = *(const float4*)(insc + kb_ + 4); \
      ih0 = *(const float4*)(insh + kb_); ih1 = *(const float4*)(insh + kb_ + 4); \
    }                                                                           \
    _Pragma("unroll")                                                           \
    for (int i_ = 0; i_ < 4; ++i_) {                                            \
      const int r_ = sr + i_ * 32;                                              \
      RA[i_] = *(const f16x8*)(wsrc + (size_t)r_ * K + kb_);                    \
      f16x8 xb = *(const f16x8*)(xsrc + (size_t)r_ * K + kb_);                  \
      if (INAFF) {                                                              \
        f16x8 nb;                                                               \
        nb[0] = (f16)fmaxf(fmaf((float)xb[0], is0.x, ih0.x), 0.f);              \
        nb[1] = (f16)fmaxf(fmaf((float)xb[1], is0.y, ih0.y), 0.f);              \
        nb[2] = (f16)fmaxf(fmaf((float)xb[2], is0.z, ih0.z), 0.f);              \
        nb[3] = (f16)fmaxf(fmaf((float)xb[3], is0.w, ih0.w), 0.f);              \
        nb[4] = (f16)fmaxf(fmaf((float)xb[4], is1.x, ih1.x), 0.f);              \
        nb[5] = (f16)fmaxf(fmaf((float)xb[5], is1.y, ih1.y), 0.f);              \
        nb[6] = (f16)fmaxf(fmaf((float)xb[6], is1.z, ih1.z), 0.f);              \
        nb[7] = (f16)fmaxf(fmaf((float)xb[7], is1.w, ih1.w), 0.f);              \
        xb = nb;                                                                \
      }                                                                         \
      RB[i_] = xb;                                                              \
    }                                                                           \
  }

#define DSWRITE(RA, RB)                                                         \
  {                                                                             \
    _Pragma("unroll")                                                           \
    for (int i_ = 0; i_ < 4; ++i_) {                                            \
      const int r_ = sr + i_ * 32;                                              \
      const int sw_ = sj ^ (r_ & 7);                                            \
      *(f16x8*)(&As[r_ * 64 + sw_ * 8]) = RA[i_];                               \
      *(f16x8*)(&Bs[r_ * 64 + sw_ * 8]) = RB[i_];                               \
    }                                                                           \
  }

template<int KS, bool INAFF, bool OUTAFF, bool STATS>
__global__ __launch_bounds__(256, 2) void gconv_k(
    const f16* __restrict__ Xt, const f16* __restrict__ Wh,
    const float* __restrict__ insc, const float* __restrict__ insh,
    const float* __restrict__ outsc, const float* __restrict__ outshB,
    f16* __restrict__ Y, float* __restrict__ ssum, float* __restrict__ ssq,
    const int M)
{
    constexpr int K = KS * 64;
    __shared__ __align__(16) f16 As[128 * 64];
    __shared__ __align__(16) f16 Bs[128 * 64];
    __shared__ float lsum[128];
    __shared__ float lsq[128];

    int bx, by;
    xcd_swz(bx, by);
    const int tid = threadIdx.x;
    const int w = tid >> 6, lane = tid & 63;
    const int llo = lane & 15, lhi = lane >> 4;
    const int wn = w >> 1, wm = w & 1;
    const int n0 = by * 128;
    const int m0 = bx * 128;
    const int sr = tid >> 3, sj = tid & 7;

    if (STATS && tid < 128) { lsum[tid] = 0.f; lsq[tid] = 0.f; }

    const f16* xsrc = Xt + (size_t)n0 * K;
    const f16* wsrc = Wh + (size_t)m0 * K;

    f32x4 acc[4][4];
#pragma unroll
    for (int nf = 0; nf < 4; ++nf)
#pragma unroll
        for (int mf = 0; mf < 4; ++mf) acc[nf][mf] = (f32x4){0.f, 0.f, 0.f, 0.f};

    f16x8 ra0[4], rb0[4], ra1[4], rb1[4];
    GLOAD(0, ra0, rb0);

#pragma unroll
    for (int kt = 0; kt < KS; ++kt) {
        if ((kt & 1) == 0) { DSWRITE(ra0, rb0); } else { DSWRITE(ra1, rb1); }
        __syncthreads();
        if (kt + 1 < KS) {
            if ((kt & 1) == 0) { GLOAD(kt + 1, ra1, rb1); }
            else               { GLOAD(kt + 1, ra0, rb0); }
        }
#pragma unroll
        for (int ks = 0; ks < 2; ++ks) {
            f16x8 af[4], bf[4];
#pragma unroll
            for (int f = 0; f < 4; ++f) {
                const int ml = wm * 64 + f * 16 + llo;
                af[f] = *(const f16x8*)(&As[ml * 64 + ((ks * 4 + lhi) ^ (ml & 7)) * 8]);
                const int nl = wn * 64 + f * 16 + llo;
                bf[f] = *(const f16x8*)(&Bs[nl * 64 + ((ks * 4 + lhi) ^ (nl & 7)) * 8]);
            }
#pragma unroll
            for (int nf = 0; nf < 4; ++nf)
#pragma unroll
                for (int mf = 0; mf < 4; ++mf)
                    acc[nf][mf] = __builtin_amdgcn_mfma_f32_16x16x32_f16(
                        af[mf], bf[nf], acc[nf][mf], 0, 0, 0);
        }
        __syncthreads();
    }

    const int bl = n0 / NPTS;
#pragma unroll
    for (int nf = 0; nf < 4; ++nf) {
        const int n = n0 + wn * 64 + nf * 16 + llo;
        f16* row = Y + (size_t)n * M + m0 + wm * 64;
#pragma unroll
        for (int mf = 0; mf < 4; ++mf) {
            const int moff = mf * 16 + 4 * lhi;
            float v0 = acc[nf][mf][0], v1 = acc[nf][mf][1];
            float v2 = acc[nf][mf][2], v3 = acc[nf][mf][3];
            if (OUTAFF) {
                const int mg = m0 + wm * 64 + moff;
                float4 s = *(const float4*)(outsc + mg);
                float4 h = *(const float4*)(outshB + (size_t)bl * M + mg);
                v0 = fmaxf(fmaf(v0, s.x, h.x), 0.f);
                v1 = fmaxf(fmaf(v1, s.y, h.y), 0.f);
                v2 = fmaxf(fmaf(v2, s.z, h.z), 0.f);
                v3 = fmaxf(fmaf(v3, s.w, h.w), 0.f);
            }
            F16x4 o;
            o.v[0] = (f16)v0; o.v[1] = (f16)v1; o.v[2] = (f16)v2; o.v[3] = (f16)v3;
            *(F16x4*)(row + moff) = o;
        }
    }
    if (STATS) {
#pragma unroll
        for (int mf = 0; mf < 4; ++mf) {
#pragma unroll
            for (int r = 0; r < 4; ++r) {
                float s = acc[0][mf][r] + acc[1][mf][r] + acc[2][mf][r] + acc[3][mf][r];
                float q = fmaf(acc[0][mf][r], acc[0][mf][r],
                          fmaf(acc[1][mf][r], acc[1][mf][r],
                          fmaf(acc[2][mf][r], acc[2][mf][r],
                               acc[3][mf][r] * acc[3][mf][r])));
#pragma unroll
                for (int d = 1; d < 16; d <<= 1) {
                    s += __shfl_xor(s, d, 64);
                    q += __shfl_xor(q, d, 64);
                }
                if (llo == 0) {
                    atomicAdd(&lsum[wm * 64 + mf * 16 + 4 * lhi + r], s);
                    atomicAdd(&lsq [wm * 64 + mf * 16 + 4 * lhi + r], q);
                }
            }
        }
        __syncthreads();
        if (tid < 128) {
            atomicAdd(&ssum[m0 + tid], lsum[tid]);
            atomicAdd(&ssq [m0 + tid], lsq [tid]);
        }
    }
}

// conv7: out[b][o][n] = tanh(b7 + sum_c w7[o][c]*relu(bn6(y6T[n][c])))
__global__ __launch_bounds__(256) void conv7T_k(
    const f16* __restrict__ y6T, const float* __restrict__ sc6,
    const float* __restrict__ sh6, const float* __restrict__ w7,
    const float* __restrict__ b7, float* __restrict__ out)
{
    __shared__ float wsc[128], wsh[128], ww[384];
    const int tid = threadIdx.x;
    if (tid < 128) { wsc[tid] = sc6[tid]; wsh[tid] = sh6[tid]; }
    for (int i = tid; i < 384; i += 256) ww[i] = w7[i];
    __syncthreads();
    const int gid = blockIdx.x * 256 + tid;
    const int b = gid >> 14, nl = gid & 16383;
    const f16* row = y6T + (size_t)gid * 128;
    float a0 = 0.f, a1 = 0.f, a2 = 0.f;
    for (int c8 = 0; c8 < 128; c8 += 8) {
        f16x8 v8 = *(const f16x8*)(row + c8);
#pragma unroll
        for (int j = 0; j < 8; ++j) {
            float hv = fmaxf(fmaf((float)v8[j], wsc[c8 + j], wsh[c8 + j]), 0.f);
            a0 = fmaf(ww[c8 + j], hv, a0);
            a1 = fmaf(ww[128 + c8 + j], hv, a1);
            a2 = fmaf(ww[256 + c8 + j], hv, a2);
        }
    }
    const float bv = b7[0];
    out[((size_t)b * 3 + 0) * NPTS + nl] = tanhf(a0 + bv);
    out[((size_t)b * 3 + 1) * NPTS + nl] = tanhf(a1 + bv);
    out[((size_t)b * 3 + 2) * NPTS + nl] = tanhf(a2 + bv);
}

// Diagnostic fallback
__global__ void fill_k(float* __restrict__ out, int nsize, float val)
{
    int i = blockIdx.x * 256 + threadIdx.x;
    if (i < nsize) out[i] = val;
}

extern "C" void kernel_launch(void* const* d_in, const int* in_sizes, int n_in,
                              void* d_out, int out_size, void* d_ws, size_t ws_size,
                              hipStream_t stream)
{
    const float* x   = (const float*)d_in[0];
    const float* w1  = (const float*)d_in[1];
    const float* g1  = (const float*)d_in[3];
    const float* be1 = (const float*)d_in[4];
    const float* w2  = (const float*)d_in[5];
    const float* g2  = (const float*)d_in[7];
    const float* be2 = (const float*)d_in[8];
    const float* w3  = (const float*)d_in[9];
    const float* g3  = (const float*)d_in[11];
    const float* be3 = (const float*)d_in[12];
    const float* w9  = (const float*)d_in[13];
    const float* b9  = (const float*)d_in[14];
    const float* w4  = (const float*)d_in[15];
    const float* g4  = (const float*)d_in[17];
    const float* be4 = (const float*)d_in[18];
    const float* w5  = (const float*)d_in[19];
    const float* g5  = (const float*)d_in[21];
    const float* be5 = (const float*)d_in[22];
    const float* w6  = (const float*)d_in[23];
    const float* g6  = (const float*)d_in[25];
    const float* be6 = (const float*)d_in[26];
    const float* w7  = (const float*)d_in[27];
    const float* b7  = (const float*)d_in[28];
    float* out = (float*)d_out;

    // ---- workspace plan (226 MiB), lifetime-aliased (unchanged) ----
    const size_t MB = 1048576u;
    const size_t need = 226 * MB;
    if (ws_size < need) {
        float val = 1000.0f + (float)(ws_size >> 20);
        fill_k<<<(out_size + 255) / 256, 256, 0, stream>>>(out, out_size, val);
        return;
    }

    char* base = (char*)d_ws;
    float* y1  = (float*)(base + 1 * MB);
    f16*   y4T = (f16*)(base + 1 * MB);
    f16*   y6T = (f16*)(base + 1 * MB);
    float* y2  = (float*)(base + 65 * MB);
    f16*   h1T = (f16*)(base + 65 * MB);
    f16*   y5T = (f16*)(base + 97 * MB);
    float* y3  = (float*)(base + 193 * MB);
    float* sm  = (float*)(base + 225 * MB);
    f16*   w5h = (f16*)(base + 225 * MB + 131072);
    f16*   w6h = w5h + 131072;   // 256*512
    f16*   w4hh = w6h + 32768;   // 128*256; w4hh is 512*64

    float* sum1 = sm + 0,     *sq1 = sm + 512,  *sc1 = sm + 1024, *sh1 = sm + 1536;
    float* sum2 = sm + 2048,  *sq2 = sm + 2560, *sc2 = sm + 3072, *sh2 = sm + 3584;
    float* sum3 = sm + 4096,  *sq3 = sm + 4608, *sc3 = sm + 5120, *sh3 = sm + 5632;
    float* sc4  = sm + 6144;
    float* sum5 = sm + 7168,  *sq5 = sm + 7680, *sc5 = sm + 8192, *sh5 = sm + 8704;
    float* sum6 = sm + 9216,  *sq6 = sm + 9728, *sc6 = sm + 10240,*sh6 = sm + 10752;
    float* vv   = sm + 11264;            // 512
    float* S1b  = sm + 11776;            // 1024
    float* Mh   = sm + 12800;            // 4096
    float* shift4b = sm + 16896;         // 16*512 -> end 25088

    hipMemsetAsync(sm, 0, 16896 * sizeof(float), stream);

    const dim3 blk(256);
    const int tiles4 = BNTOT / 1024;     // 256 n-tiles (PT=4)

    // fp16 weight copies
    wcvt_k<<<(256 * 512 + 255) / 256, blk, 0, stream>>>(w5, w5h, 256, 512, 512, 0);
    wcvt_k<<<(128 * 256 + 255) / 256, blk, 0, stream>>>(w6, w6h, 128, 256, 256, 0);
    wcvt_k<<<(512 * 64 + 255) / 256, blk, 0, stream>>>(w4, w4hh, 512, 64, 96, 32);

    // conv1..conv3 (fp32; per-element FMA chains identical to round 8)
    conv_k<4, 32, 0, true><<<dim3(2, tiles4), blk, 0, stream>>>(
        x, w1, nullptr, nullptr, y1, sum1, sq1, 64);
    bnstats_k<<<1, 256, 0, stream>>>(sum1, sq1, g1, be1, sc1, sh1, 64);

    conv_k<64, 32, 1, true><<<dim3(4, tiles4), blk, 0, stream>>>(
        y1, w2, sc1, sh1, y2, sum2, sq2, 128);
    bnstats_k<<<1, 256, 0, stream>>>(sum2, sq2, g2, be2, sc2, sh2, 128);

    conv_k<128, 16, 1, true><<<dim3(2, tiles4), blk, 0, stream>>>(
        y2, w3, sc2, sh2, y3, sum3, sq3, 32);
    bnstats_k<<<1, 256, 0, stream>>>(sum3, sq3, g3, be3, sc3, sh3, 32);

    softpool_k<<<512, blk, NPTS * sizeof(float), stream>>>(y3, sc3, sh3, w9, b9, vv);

    // h1T + S1b, MFMA SYRK moment, BN4 (fused per-(b,o) shift)
    transformT_k<<<16 * 256, blk, 0, stream>>>(y1, sc1, sh1, h1T, S1b);
    msyrk_k<<<512, blk, 0, stream>>>(h1T, Mh);
    bnstats45_k<<<1, 512, 0, stream>>>(w4, vv, S1b, Mh, g4, be4, sc4, shift4b);

    // conv4+conv5 in 4 batch-chunks (tiled MFMA GEMM); y4T bounce in y1 region
    for (int q = 0; q < 4; ++q) {
        const f16* h1q = h1T + (size_t)q * 4 * NPTS * 64;
        f16* y5q = y5T + (size_t)q * 4 * NPTS * 256;
        gconv_k<1, false, true, false><<<dim3(4, 512), blk, 0, stream>>>(
            h1q, w4hh, nullptr, nullptr, sc4, shift4b + (size_t)q * 4 * 512,
            y4T, nullptr, nullptr, 512);
        gconv_k<8, false, false, true><<<dim3(2, 512), blk, 0, stream>>>(
            y4T, w5h, nullptr, nullptr, nullptr, nullptr,
            y5q, sum5, sq5, 256);
    }
    bnstats_k<<<1, 256, 0, stream>>>(sum5, sq5, g5, be5, sc5, sh5, 256);

    // conv6: K=256 -> M=128, INAFF(bn5+relu at staging), raw + stats
    gconv_k<4, true, false, true><<<dim3(1, 2048), blk, 0, stream>>>(
        y5T, w6h, sc5, sh5, nullptr, nullptr,
        y6T, sum6, sq6, 128);
    bnstats_k<<<1, 256, 0, stream>>>(sum6, sq6, g6, be6, sc6, sh6, 128);

    // conv7: VALU, bn6+relu on load, tanh out
    conv7T_k<<<BNTOT / 256, blk, 0, stream>>>(y6T, sc6, sh6, w7, b7, out);
}

// Round 11
// 884.464 us; speedup vs baseline: 1.5420x; 1.5420x over previous
//
#include <hip/hip_runtime.h>
#include <hip/hip_fp16.h>
#include <math.h>

#define NPTS 16384
#define NB 16
#define BNTOT (NB * NPTS)
#define NP 16

typedef _Float16 f16;
typedef __attribute__((ext_vector_type(8))) _Float16 f16x8;
typedef __attribute__((ext_vector_type(4))) float f32x4;

struct alignas(8) F16x4 { f16 v[4]; };

// XCD-aware block swizzle (proved: FETCH 131->33MB on conv2). Bijective when
// total blocks % 8 == 0; keeps all x-tiles of one y-slab on one XCD.
__device__ inline void xcd_swz(int& bx, int& by)
{
    const int flatb = blockIdx.y * gridDim.x + blockIdx.x;
    const int slot = flatb >> 3, xcd = flatb & 7;
    bx = slot % gridDim.x;
    by = (slot / gridDim.x) * 8 + xcd;
}

// ---------------------------------------------------------------------------
// fp32 VALU conv (conv1..conv3), PT=4, round-8 FMA chains (bit-identical ->
// sort indices preserved). launch_bounds(256,2): PT=4 needs ~220 unified
// VGPR+AGPR (128 acc in AGPRs); (256,3) forced scratch spill (round-10: 1.4GB
// writes, 6x slowdown). o-fastest staging: LDS write banks = o%32 -> 0
// conflicts (verified round 10). XCD swizzle keeps o-tiles on one XCD.
// ---------------------------------------------------------------------------
template<int CIN, int OT, int MODE, bool STATS>
__global__ __launch_bounds__(256, 2) void conv_k(
    const float* __restrict__ X, const float* __restrict__ W,
    const float* __restrict__ insc, const float* __restrict__ insh,
    float* __restrict__ Y, float* __restrict__ ssum, float* __restrict__ ssq,
    int COUT)
{
    constexpr int PT = 4;
    constexpr int NT = 256 * PT;               // 1024 points per block
    constexpr int CC = (CIN < 128) ? CIN : 128;
    __shared__ __align__(16) float Ws[CC][OT];
    __shared__ float lsum[OT];
    __shared__ float lsq[OT];

    int bx, by;
    xcd_swz(bx, by);
    const int tid = threadIdx.x;
    const int b = (by * NT) / NPTS;
    const int n = (by * NT) % NPTS + tid * PT;
    const int obase = bx * OT;

    if (STATS) {
        for (int i = tid; i < OT; i += 256) { lsum[i] = 0.f; lsq[i] = 0.f; }
    }

    float acc[OT][PT];
#pragma unroll
    for (int o = 0; o < OT; ++o)
#pragma unroll
        for (int p = 0; p < PT; ++p) acc[o][p] = 0.f;

    const float* Xb = X + (size_t)b * CIN * NPTS;

    for (int c0 = 0; c0 < CIN; c0 += CC) {
        // o-fastest staging: LDS write banks = o%32 (2 lanes/bank, free);
        // W reads strided by CIN but W <= 32KB -> L1/L2-resident.
        for (int i = tid; i < CC * OT; i += 256) {
            int o = i % OT, c = i / OT;
            int oo = obase + o;
            Ws[c][o] = (oo < COUT) ? W[(size_t)oo * CIN + (c0 + c)] : 0.f;
        }
        __syncthreads();
#pragma unroll 2
        for (int c = 0; c < CC; ++c) {
            const int cx = c0 + c;
            float xv[PT];
            float4 t = *(const float4*)(Xb + (size_t)cx * NPTS + n);
            xv[0] = t.x; xv[1] = t.y; xv[2] = t.z; xv[3] = t.w;
            if (MODE == 1) {
                float s = insc[cx], h = insh[cx];
#pragma unroll
                for (int p = 0; p < PT; ++p)
                    xv[p] = fmaxf(fmaf(xv[p], s, h), 0.f);
            }
            const float4* wrow = (const float4*)(&Ws[c][0]);
#pragma unroll
            for (int o4 = 0; o4 < OT / 4; ++o4) {
                float4 w = wrow[o4];
#pragma unroll
                for (int p = 0; p < PT; ++p) {
                    acc[o4 * 4 + 0][p] = fmaf(w.x, xv[p], acc[o4 * 4 + 0][p]);
                    acc[o4 * 4 + 1][p] = fmaf(w.y, xv[p], acc[o4 * 4 + 1][p]);
                    acc[o4 * 4 + 2][p] = fmaf(w.z, xv[p], acc[o4 * 4 + 2][p]);
                    acc[o4 * 4 + 3][p] = fmaf(w.w, xv[p], acc[o4 * 4 + 3][p]);
                }
            }
        }
        __syncthreads();
    }

#pragma unroll
    for (int o = 0; o < OT; ++o) {
        const int oo = obase + o;
        if (oo < COUT) {
            float v[PT];
#pragma unroll
            for (int p = 0; p < PT; ++p) v[p] = acc[o][p];
            *(float4*)(Y + ((size_t)b * COUT + oo) * NPTS + n) =
                make_float4(v[0], v[1], v[2], v[3]);
            if (STATS) {
                float s = (v[0] + v[1]) + (v[2] + v[3]);
                float q = fmaf(v[0], v[0], fmaf(v[1], v[1], fmaf(v[2], v[2], v[3] * v[3])));
#pragma unroll
                for (int d = 32; d >= 1; d >>= 1) {
                    s += __shfl_xor(s, d, 64);
                    q += __shfl_xor(q, d, 64);
                }
                if ((tid & 63) == 0) {
                    atomicAdd(&lsum[o], s);
                    atomicAdd(&lsq[o], q);
                }
            }
        }
    }
    if (STATS) {
        __syncthreads();
        for (int i = tid; i < OT; i += 256) {
            int oo = obase + i;
            if (oo < COUT) {
                atomicAdd(&ssum[oo], lsum[i]);
                atomicAdd(&ssq[oo], lsq[i]);
            }
        }
    }
}

// per-channel BN fold: scale = g/sqrt(var+eps), shift = be - mean*scale
__global__ void bnstats_k(const float* __restrict__ ssum, const float* __restrict__ ssq,
                          const float* __restrict__ g, const float* __restrict__ be,
                          float* __restrict__ scale, float* __restrict__ shift, int C)
{
    int c = blockIdx.x * blockDim.x + threadIdx.x;
    if (c >= C) return;
    const float inv = 1.0f / (float)BNTOT;
    float m = ssum[c] * inv;
    float var = fmaf(ssq[c], inv, -m * m);
    float sc = g[c] / sqrtf(var + 1e-5f);
    scale[c] = sc;
    shift[c] = fmaf(-m, sc, be[c]);
}

// SoftPool (UNCHANGED): stable 16-smallest per (b,k), then gather-dot.
__global__ __launch_bounds__(256) void softpool_k(
    const float* __restrict__ y3, const float* __restrict__ sc3,
    const float* __restrict__ sh3, const float* __restrict__ w9,
    const float* __restrict__ b9, float* __restrict__ vout)
{
    extern __shared__ float vals[];
    __shared__ int sidx[NP];
    __shared__ float wv[4];
    __shared__ int wi[4];
    __shared__ float ps[4];

    const int tid = threadIdx.x;
    const int b = blockIdx.x >> 5;
    const int k = blockIdx.x & 31;

    const float* src = y3 + ((size_t)b * 32 + k) * NPTS;
    const float sck = sc3[k], shk = sh3[k];
    for (int i = tid; i < NPTS; i += 256) vals[i] = fmaf(src[i], sck, shk);
    __syncthreads();

    for (int p = 0; p < NP; ++p) {
        float bv = INFINITY;
        int bi = 0x7fffffff;
        for (int i = tid; i < NPTS; i += 256) {
            float x = vals[i];
            if (x < bv) { bv = x; bi = i; }
        }
#pragma unroll
        for (int d = 32; d >= 1; d >>= 1) {
            float ov = __shfl_xor(bv, d, 64);
            int oi = __shfl_xor(bi, d, 64);
            if (ov < bv || (ov == bv && oi < bi)) { bv = ov; bi = oi; }
        }
        if ((tid & 63) == 0) { wv[tid >> 6] = bv; wi[tid >> 6] = bi; }
        __syncthreads();
        if (tid == 0) {
            for (int w = 1; w < 4; ++w)
                if (wv[w] < bv || (wv[w] == bv && wi[w] < bi)) { bv = wv[w]; bi = wi[w]; }
            sidx[p] = bi;
            vals[bi] = INFINITY;
        }
        __syncthreads();
    }

    float part = 0.f;
    for (int i = tid; i < 32 * NP; i += 256) {
        int c = i >> 4, p = i & 15;
        float h = fmaf(y3[((size_t)b * 32 + c) * NPTS + sidx[p]], sc3[c], sh3[c]);
        part += w9[c * NP + p] * h;
    }
#pragma unroll
    for (int d = 32; d >= 1; d >>= 1) part += __shfl_xor(part, d, 64);
    if ((tid & 63) == 0) ps[tid >> 6] = part;
    __syncthreads();
    if (tid == 0) vout[b * 32 + k] = ps[0] + ps[1] + ps[2] + ps[3] + b9[0];
}

// h1T[b][n][64] fp16 = relu(bn1(y1)), LDS transpose; S1b per-(b,c) sums.
__global__ __launch_bounds__(256) void transformT_k(
    const float* __restrict__ y1, const float* __restrict__ sc,
    const float* __restrict__ sh, f16* __restrict__ h1T, float* __restrict__ S1b)
{
    __shared__ float arr[64][65];
    __shared__ float s1loc[64];
    const int tid = threadIdx.x;
    const int b = blockIdx.x >> 8;
    const int n0 = (blockIdx.x & 255) * 64;
    if (tid < 64) s1loc[tid] = 0.f;

    const int c = tid >> 2, j4 = tid & 3;
    const float scv = sc[c], shv = sh[c];
    const float* src = y1 + ((size_t)b * 64 + c) * NPTS + n0 + j4 * 16;
    float ls = 0.f;
#pragma unroll
    for (int j = 0; j < 4; ++j) {
        float4 v = *(const float4*)(src + j * 4);
        float r0 = fmaxf(fmaf(v.x, scv, shv), 0.f);
        float r1 = fmaxf(fmaf(v.y, scv, shv), 0.f);
        float r2 = fmaxf(fmaf(v.z, scv, shv), 0.f);
        float r3 = fmaxf(fmaf(v.w, scv, shv), 0.f);
        arr[j4 * 16 + j * 4 + 0][c] = r0;
        arr[j4 * 16 + j * 4 + 1][c] = r1;
        arr[j4 * 16 + j * 4 + 2][c] = r2;
        arr[j4 * 16 + j * 4 + 3][c] = r3;
        ls += (r0 + r1) + (r2 + r3);
    }
    ls += __shfl_xor(ls, 1, 64);
    ls += __shfl_xor(ls, 2, 64);
    if (j4 == 0) atomicAdd(&s1loc[c], ls);
    __syncthreads();

    const int n = tid >> 2, cj = (tid & 3) * 16;
    f16x8 h0, h1v;
#pragma unroll
    for (int jj = 0; jj < 8; ++jj) h0[jj] = (f16)arr[n][cj + jj];
#pragma unroll
    for (int jj = 0; jj < 8; ++jj) h1v[jj] = (f16)arr[n][cj + 8 + jj];
    f16* dst = h1T + ((size_t)b * NPTS + n0 + n) * 64 + cj;
    *(f16x8*)(dst) = h0;
    *(f16x8*)(dst + 8) = h1v;

    if (tid < 64) atomicAdd(&S1b[b * 64 + tid], s1loc[tid]);
}

// MFMA SYRK (UNCHANGED): M[i][j] = sum_r H[r][i]*H[r][j] over h1T.
__global__ __launch_bounds__(256, 2) void msyrk_k(const f16* __restrict__ h1T,
                                                  float* __restrict__ M)
{
    __shared__ float Mlds[4][4096];
    const int tid = threadIdx.x;
    const int lane = tid & 63;
    const int llo = lane & 15, lhi = lane >> 4;
    const int wv = tid >> 6;
    const int gw = blockIdx.x * 4 + wv;
    constexpr int SPW = (BNTOT / 32) / 2048;

    f32x4 acc[4][4];
#pragma unroll
    for (int ti = 0; ti < 4; ++ti)
#pragma unroll
        for (int tj = 0; tj < 4; ++tj) acc[ti][tj] = (f32x4){0.f, 0.f, 0.f, 0.f};

#pragma unroll
    for (int s = 0; s < SPW; ++s) {
        const size_t r0 = (size_t)gw * (SPW * 32) + (size_t)s * 32 + 8 * lhi;
        const f16* base = h1T + r0 * 64 + llo;
        f16x8 f[4];
#pragma unroll
        for (int t = 0; t < 4; ++t)
#pragma unroll
            for (int i = 0; i < 8; ++i)
                f[t][i] = base[(size_t)i * 64 + t * 16];
#pragma unroll
        for (int ti = 0; ti < 4; ++ti)
#pragma unroll
            for (int tj = 0; tj < 4; ++tj)
                acc[ti][tj] = __builtin_amdgcn_mfma_f32_16x16x32_f16(
                    f[ti], f[tj], acc[ti][tj], 0, 0, 0);
    }

#pragma unroll
    for (int ti = 0; ti < 4; ++ti)
#pragma unroll
        for (int tj = 0; tj < 4; ++tj)
#pragma unroll
            for (int r = 0; r < 4; ++r)
                Mlds[wv][(ti * 16 + 4 * lhi + r) * 64 + tj * 16 + llo] = acc[ti][tj][r];
    __syncthreads();
    for (int i = tid; i < 4096; i += 256)
        atomicAdd(&M[i], (Mlds[0][i] + Mlds[1][i]) + (Mlds[2][i] + Mlds[3][i]));
}

// BN4 from input moments; emits per-(b,o) fused shift.
__global__ void bnstats45_k(const float* __restrict__ w4, const float* __restrict__ vv,
                            const float* __restrict__ S1b, const float* __restrict__ M,
                            const float* __restrict__ g, const float* __restrict__ be,
                            float* __restrict__ sc4, float* __restrict__ shift4b)
{
    __shared__ float vvL[512], sbL[1024], ML[4096];
    const int tid = threadIdx.x;
    for (int i = tid; i < 512; i += 512) vvL[i] = vv[i];
    for (int i = tid; i < 1024; i += 512) sbL[i] = S1b[i];
    for (int i = tid; i < 4096; i += 512) ML[i] = M[i];
    __syncthreads();
    const int o = tid;
    float wg[32], wh[64];
#pragma unroll
    for (int i = 0; i < 32; ++i) wg[i] = w4[o * 96 + i];
#pragma unroll
    for (int j = 0; j < 64; ++j) wh[j] = w4[o * 96 + 32 + j];
    float gbv[16];
    float sumy = 0.f, sumsq = 0.f;
#pragma unroll
    for (int b = 0; b < 16; ++b) {
        float gb = 0.f, hb = 0.f;
#pragma unroll
        for (int i = 0; i < 32; ++i) gb = fmaf(wg[i], vvL[b * 32 + i], gb);
#pragma unroll
        for (int j = 0; j < 64; ++j) hb = fmaf(wh[j], sbL[b * 64 + j], hb);
        gbv[b] = gb;
        sumy += (float)NPTS * gb + hb;
        sumsq += (float)NPTS * gb * gb + 2.f * gb * hb;
    }
    for (int j = 0; j < 64; ++j) {
        float t = 0.f;
#pragma unroll
        for (int j2 = 0; j2 < 64; ++j2) t = fmaf(ML[j * 64 + j2], wh[j2], t);
        sumsq = fmaf(wh[j], t, sumsq);
    }
    const float inv = 1.0f / (float)BNTOT;
    float m = sumy * inv;
    float var = fmaf(sumsq, inv, -m * m);
    float s = g[o] / sqrtf(var + 1e-5f);
    float sh4v = fmaf(-m, s, be[o]);
    sc4[o] = s;
#pragma unroll
    for (int b = 0; b < 16; ++b)
        shift4b[b * 512 + o] = fmaf(gbv[b], s, sh4v);
}

// fp32 -> fp16 weight conversion (optionally a column slice of src)
__global__ void wcvt_k(const float* __restrict__ src, f16* __restrict__ dst,
                       int rows, int cols, int srcStride, int srcOff)
{
    int i = blockIdx.x * 256 + threadIdx.x;
    if (i < rows * cols) {
        int r = i / cols, c = i % cols;
        dst[i] = (f16)src[(size_t)r * srcStride + srcOff + c];
    }
}

// ---------------------------------------------------------------------------
// LDS-tiled MFMA GEMM (round-7 structure + XCD swizzle). UNCHANGED.
// ---------------------------------------------------------------------------
#define GLOAD(KT, RA, RB)                                                       \
  {                                                                             \
    const int kb_ = (KT) * 64 + sj * 8;                                         \
    float4 is0, is1, ih0, ih1;                                                  \
    if (INAFF) {                                                                \
      is0 = *(const float4*)(insc + kb_); is1 = *(const float4*)(insc + kb_ + 4); \
      ih0 = *(const float4*)(insh + kb_); ih1 = *(const float4*)(insh + kb_ + 4); \
    }                                                                           \
    _Pragma("unroll")                                                           \
    for (int i_ = 0; i_ < 4; ++i_) {                                            \
      const int r_ = sr + i_ * 32;                                              \
      RA[i_] = *(const f16x8*)(wsrc + (size_t)r_ * K + kb_);                    \
      f16x8 xb = *(const f16x8*)(xsrc + (size_t)r_ * K + kb_);                  \
      if (INAFF) {                                                              \
        f16x8 nb;                                                               \
        nb[0] = (f16)fmaxf(fmaf((float)xb[0], is0.x, ih0.x), 0.f);              \
        nb[1] = (f16)fmaxf(fmaf((float)xb[1], is0.y, ih0.y), 0.f);              \
        nb[2] = (f16)fmaxf(fmaf((float)xb[2], is0.z, ih0.z), 0.f);              \
        nb[3] = (f16)fmaxf(fmaf((float)xb[3], is0.w, ih0.w), 0.f);              \
        nb[4] = (f16)fmaxf(fmaf((float)xb[4], is1.x, ih1.x), 0.f);              \
        nb[5] = (f16)fmaxf(fmaf((float)xb[5], is1.y, ih1.y), 0.f);              \
        nb[6] = (f16)fmaxf(fmaf((float)xb[6], is1.z, ih1.z), 0.f);              \
        nb[7] = (f16)fmaxf(fmaf((float)xb[7], is1.w, ih1.w), 0.f);              \
        xb = nb;                                                                \
      }                                                                         \
      RB[i_] = xb;                                                              \
    }                                                                           \
  }

#define DSWRITE(RA, RB)                                                         \
  {                                                                             \
    _Pragma("unroll")                                                           \
    for (int i_ = 0; i_ < 4; ++i_) {                                            \
      const int r_ = sr + i_ * 32;                                              \
      const int sw_ = sj ^ (r_ & 7);                                            \
      *(f16x8*)(&As[r_ * 64 + sw_ * 8]) = RA[i_];                               \
      *(f16x8*)(&Bs[r_ * 64 + sw_ * 8]) = RB[i_];                               \
    }                                                                           \
  }

template<int KS, bool INAFF, bool OUTAFF, bool STATS>
__global__ __launch_bounds__(256, 2) void gconv_k(
    const f16* __restrict__ Xt, const f16* __restrict__ Wh,
    const float* __restrict__ insc, const float* __restrict__ insh,
    const float* __restrict__ outsc, const float* __restrict__ outshB,
    f16* __restrict__ Y, float* __restrict__ ssum, float* __restrict__ ssq,
    const int M)
{
    constexpr int K = KS * 64;
    __shared__ __align__(16) f16 As[128 * 64];
    __shared__ __align__(16) f16 Bs[128 * 64];
    __shared__ float lsum[128];
    __shared__ float lsq[128];

    int bx, by;
    xcd_swz(bx, by);
    const int tid = threadIdx.x;
    const int w = tid >> 6, lane = tid & 63;
    const int llo = lane & 15, lhi = lane >> 4;
    const int wn = w >> 1, wm = w & 1;
    const int n0 = by * 128;
    const int m0 = bx * 128;
    const int sr = tid >> 3, sj = tid & 7;

    if (STATS && tid < 128) { lsum[tid] = 0.f; lsq[tid] = 0.f; }

    const f16* xsrc = Xt + (size_t)n0 * K;
    const f16* wsrc = Wh + (size_t)m0 * K;

    f32x4 acc[4][4];
#pragma unroll
    for (int nf = 0; nf < 4; ++nf)
#pragma unroll
        for (int mf = 0; mf < 4; ++mf) acc[nf][mf] = (f32x4){0.f, 0.f, 0.f, 0.f};

    f16x8 ra0[4], rb0[4], ra1[4], rb1[4];
    GLOAD(0, ra0, rb0);

#pragma unroll
    for (int kt = 0; kt < KS; ++kt) {
        if ((kt & 1) == 0) { DSWRITE(ra0, rb0); } else { DSWRITE(ra1, rb1); }
        __syncthreads();
        if (kt + 1 < KS) {
            if ((kt & 1) == 0) { GLOAD(kt + 1, ra1, rb1); }
            else               { GLOAD(kt + 1, ra0, rb0); }
        }
#pragma unroll
        for (int ks = 0; ks < 2; ++ks) {
            f16x8 af[4], bf[4];
#pragma unroll
            for (int f = 0; f < 4; ++f) {
                const int ml = wm * 64 + f * 16 + llo;
                af[f] = *(const f16x8*)(&As[ml * 64 + ((ks * 4 + lhi) ^ (ml & 7)) * 8]);
                const int nl = wn * 64 + f * 16 + llo;
                bf[f] = *(const f16x8*)(&Bs[nl * 64 + ((ks * 4 + lhi) ^ (nl & 7)) * 8]);
            }
#pragma unroll
            for (int nf = 0; nf < 4; ++nf)
#pragma unroll
                for (int mf = 0; mf < 4; ++mf)
                    acc[nf][mf] = __builtin_amdgcn_mfma_f32_16x16x32_f16(
                        af[mf], bf[nf], acc[nf][mf], 0, 0, 0);
        }
        __syncthreads();
    }

    const int bl = n0 / NPTS;
#pragma unroll
    for (int nf = 0; nf < 4; ++nf) {
        const int n = n0 + wn * 64 + nf * 16 + llo;
        f16* row = Y + (size_t)n * M + m0 + wm * 64;
#pragma unroll
        for (int mf = 0; mf < 4; ++mf) {
            const int moff = mf * 16 + 4 * lhi;
            float v0 = acc[nf][mf][0], v1 = acc[nf][mf][1];
            float v2 = acc[nf][mf][2], v3 = acc[nf][mf][3];
            if (OUTAFF) {
                const int mg = m0 + wm * 64 + moff;
                float4 s = *(const float4*)(outsc + mg);
                float4 h = *(const float4*)(outshB + (size_t)bl * M + mg);
                v0 = fmaxf(fmaf(v0, s.x, h.x), 0.f);
                v1 = fmaxf(fmaf(v1, s.y, h.y), 0.f);
                v2 = fmaxf(fmaf(v2, s.z, h.z), 0.f);
                v3 = fmaxf(fmaf(v3, s.w, h.w), 0.f);
            }
            F16x4 o;
            o.v[0] = (f16)v0; o.v[1] = (f16)v1; o.v[2] = (f16)v2; o.v[3] = (f16)v3;
            *(F16x4*)(row + moff) = o;
        }
    }
    if (STATS) {
#pragma unroll
        for (int mf = 0; mf < 4; ++mf) {
#pragma unroll
            for (int r = 0; r < 4; ++r) {
                float s = acc[0][mf][r] + acc[1][mf][r] + acc[2][mf][r] + acc[3][mf][r];
                float q = fmaf(acc[0][mf][r], acc[0][mf][r],
                          fmaf(acc[1][mf][r], acc[1][mf][r],
                          fmaf(acc[2][mf][r], acc[2][mf][r],
                               acc[3][mf][r] * acc[3][mf][r])));
#pragma unroll
                for (int d = 1; d < 16; d <<= 1) {
                    s += __shfl_xor(s, d, 64);
                    q += __shfl_xor(q, d, 64);
                }
                if (llo == 0) {
                    atomicAdd(&lsum[wm * 64 + mf * 16 + 4 * lhi + r], s);
                    atomicAdd(&lsq [wm * 64 + mf * 16 + 4 * lhi + r], q);
                }
            }
        }
        __syncthreads();
        if (tid < 128) {
            atomicAdd(&ssum[m0 + tid], lsum[tid]);
            atomicAdd(&ssq [m0 + tid], lsq [tid]);
        }
    }
}

// conv7: out[b][o][n] = tanh(b7 + sum_c w7[o][c]*relu(bn6(y6T[n][c])))
__global__ __launch_bounds__(256) void conv7T_k(
    const f16* __restrict__ y6T, const float* __restrict__ sc6,
    const float* __restrict__ sh6, const float* __restrict__ w7,
    const float* __restrict__ b7, float* __restrict__ out)
{
    __shared__ float wsc[128], wsh[128], ww[384];
    const int tid = threadIdx.x;
    if (tid < 128) { wsc[tid] = sc6[tid]; wsh[tid] = sh6[tid]; }
    for (int i = tid; i < 384; i += 256) ww[i] = w7[i];
    __syncthreads();
    const int gid = blockIdx.x * 256 + tid;
    const int b = gid >> 14, nl = gid & 16383;
    const f16* row = y6T + (size_t)gid * 128;
    float a0 = 0.f, a1 = 0.f, a2 = 0.f;
    for (int c8 = 0; c8 < 128; c8 += 8) {
        f16x8 v8 = *(const f16x8*)(row + c8);
#pragma unroll
        for (int j = 0; j < 8; ++j) {
            float hv = fmaxf(fmaf((float)v8[j], wsc[c8 + j], wsh[c8 + j]), 0.f);
            a0 = fmaf(ww[c8 + j], hv, a0);
            a1 = fmaf(ww[128 + c8 + j], hv, a1);
            a2 = fmaf(ww[256 + c8 + j], hv, a2);
        }
    }
    const float bv = b7[0];
    out[((size_t)b * 3 + 0) * NPTS + nl] = tanhf(a0 + bv);
    out[((size_t)b * 3 + 1) * NPTS + nl] = tanhf(a1 + bv);
    out[((size_t)b * 3 + 2) * NPTS + nl] = tanhf(a2 + bv);
}

// Diagnostic fallback
__global__ void fill_k(float* __restrict__ out, int nsize, float val)
{
    int i = blockIdx.x * 256 + threadIdx.x;
    if (i < nsize) out[i] = val;
}

extern "C" void kernel_launch(void* const* d_in, const int* in_sizes, int n_in,
                              void* d_out, int out_size, void* d_ws, size_t ws_size,
                              hipStream_t stream)
{
    const float* x   = (const float*)d_in[0];
    const float* w1  = (const float*)d_in[1];
    const float* g1  = (const float*)d_in[3];
    const float* be1 = (const float*)d_in[4];
    const float* w2  = (const float*)d_in[5];
    const float* g2  = (const float*)d_in[7];
    const float* be2 = (const float*)d_in[8];
    const float* w3  = (const float*)d_in[9];
    const float* g3  = (const float*)d_in[11];
    const float* be3 = (const float*)d_in[12];
    const float* w9  = (const float*)d_in[13];
    const float* b9  = (const float*)d_in[14];
    const float* w4  = (const float*)d_in[15];
    const float* g4  = (const float*)d_in[17];
    const float* be4 = (const float*)d_in[18];
    const float* w5  = (const float*)d_in[19];
    const float* g5  = (const float*)d_in[21];
    const float* be5 = (const float*)d_in[22];
    const float* w6  = (const float*)d_in[23];
    const float* g6  = (const float*)d_in[25];
    const float* be6 = (const float*)d_in[26];
    const float* w7  = (const float*)d_in[27];
    const float* b7  = (const float*)d_in[28];
    float* out = (float*)d_out;

    // ---- workspace plan (226 MiB), lifetime-aliased (unchanged) ----
    const size_t MB = 1048576u;
    const size_t need = 226 * MB;
    if (ws_size < need) {
        float val = 1000.0f + (float)(ws_size >> 20);
        fill_k<<<(out_size + 255) / 256, 256, 0, stream>>>(out, out_size, val);
        return;
    }

    char* base = (char*)d_ws;
    float* y1  = (float*)(base + 1 * MB);
    f16*   y4T = (f16*)(base + 1 * MB);
    f16*   y6T = (f16*)(base + 1 * MB);
    float* y2  = (float*)(base + 65 * MB);
    f16*   h1T = (f16*)(base + 65 * MB);
    f16*   y5T = (f16*)(base + 97 * MB);
    float* y3  = (float*)(base + 193 * MB);
    float* sm  = (float*)(base + 225 * MB);
    f16*   w5h = (f16*)(base + 225 * MB + 131072);
    f16*   w6h = w5h + 131072;   // 256*512
    f16*   w4hh = w6h + 32768;   // 128*256; w4hh is 512*64

    float* sum1 = sm + 0,     *sq1 = sm + 512,  *sc1 = sm + 1024, *sh1 = sm + 1536;
    float* sum2 = sm + 2048,  *sq2 = sm + 2560, *sc2 = sm + 3072, *sh2 = sm + 3584;
    float* sum3 = sm + 4096,  *sq3 = sm + 4608, *sc3 = sm + 5120, *sh3 = sm + 5632;
    float* sc4  = sm + 6144;
    float* sum5 = sm + 7168,  *sq5 = sm + 7680, *sc5 = sm + 8192, *sh5 = sm + 8704;
    float* sum6 = sm + 9216,  *sq6 = sm + 9728, *sc6 = sm + 10240,*sh6 = sm + 10752;
    float* vv   = sm + 11264;            // 512
    float* S1b  = sm + 11776;            // 1024
    float* Mh   = sm + 12800;            // 4096
    float* shift4b = sm + 16896;         // 16*512 -> end 25088

    hipMemsetAsync(sm, 0, 16896 * sizeof(float), stream);

    const dim3 blk(256);
    const int tiles4 = BNTOT / 1024;     // 256 n-tiles (PT=4)

    // fp16 weight copies
    wcvt_k<<<(256 * 512 + 255) / 256, blk, 0, stream>>>(w5, w5h, 256, 512, 512, 0);
    wcvt_k<<<(128 * 256 + 255) / 256, blk, 0, stream>>>(w6, w6h, 128, 256, 256, 0);
    wcvt_k<<<(512 * 64 + 255) / 256, blk, 0, stream>>>(w4, w4hh, 512, 64, 96, 32);

    // conv1..conv3 (fp32; per-element FMA chains identical to round 8)
    conv_k<4, 32, 0, true><<<dim3(2, tiles4), blk, 0, stream>>>(
        x, w1, nullptr, nullptr, y1, sum1, sq1, 64);
    bnstats_k<<<1, 256, 0, stream>>>(sum1, sq1, g1, be1, sc1, sh1, 64);

    conv_k<64, 32, 1, true><<<dim3(4, tiles4), blk, 0, stream>>>(
        y1, w2, sc1, sh1, y2, sum2, sq2, 128);
    bnstats_k<<<1, 256, 0, stream>>>(sum2, sq2, g2, be2, sc2, sh2, 128);

    conv_k<128, 16, 1, true><<<dim3(2, tiles4), blk, 0, stream>>>(
        y2, w3, sc2, sh2, y3, sum3, sq3, 32);
    bnstats_k<<<1, 256, 0, stream>>>(sum3, sq3, g3, be3, sc3, sh3, 32);

    softpool_k<<<512, blk, NPTS * sizeof(float), stream>>>(y3, sc3, sh3, w9, b9, vv);

    // h1T + S1b, MFMA SYRK moment, BN4 (fused per-(b,o) shift)
    transformT_k<<<16 * 256, blk, 0, stream>>>(y1, sc1, sh1, h1T, S1b);
    msyrk_k<<<512, blk, 0, stream>>>(h1T, Mh);
    bnstats45_k<<<1, 512, 0, stream>>>(w4, vv, S1b, Mh, g4, be4, sc4, shift4b);

    // conv4+conv5 in 4 batch-chunks (tiled MFMA GEMM); y4T bounce in y1 region
    for (int q = 0; q < 4; ++q) {
        const f16* h1q = h1T + (size_t)q * 4 * NPTS * 64;
        f16* y5q = y5T + (size_t)q * 4 * NPTS * 256;
        gconv_k<1, false, true, false><<<dim3(4, 512), blk, 0, stream>>>(
            h1q, w4hh, nullptr, nullptr, sc4, shift4b + (size_t)q * 4 * 512,
            y4T, nullptr, nullptr, 512);
        gconv_k<8, false, false, true><<<dim3(2, 512), blk, 0, stream>>>(
            y4T, w5h, nullptr, nullptr, nullptr, nullptr,
            y5q, sum5, sq5, 256);
    }
    bnstats_k<<<1, 256, 0, stream>>>(sum5, sq5, g5, be5, sc5, sh5, 256);

    // conv6: K=256 -> M=128, INAFF(bn5+relu at staging), raw + stats
    gconv_k<4, true, false, true><<<dim3(1, 2048), blk, 0, stream>>>(
        y5T, w6h, sc5, sh5, nullptr, nullptr,
        y6T, sum6, sq6, 128);
    bnstats_k<<<1, 256, 0, stream>>>(sum6, sq6, g6, be6, sc6, sh6, 128);

    // conv7: VALU, bn6+relu on load, tanh out
    conv7T_k<<<BNTOT / 256, blk, 0, stream>>>(y6T, sc6, sh6, w7, b7, out);
}

// Round 12
// 877.387 us; speedup vs baseline: 1.5545x; 1.0081x over previous
//
#include <hip/hip_runtime.h>
#include <hip/hip_fp16.h>
#include <math.h>

#define NPTS 16384
#define NB 16
#define BNTOT (NB * NPTS)
#define NP 16

typedef _Float16 f16;
typedef __attribute__((ext_vector_type(8))) _Float16 f16x8;
typedef __attribute__((ext_vector_type(4))) float f32x4;

struct alignas(8) F16x4 { f16 v[4]; };

// XCD-aware block swizzle (proved: FETCH 131->33MB on conv2). Bijective when
// total blocks % 8 == 0; keeps all x-tiles of one y-slab on one XCD.
__device__ inline void xcd_swz(int& bx, int& by)
{
    const int flatb = blockIdx.y * gridDim.x + blockIdx.x;
    const int slot = flatb >> 3, xcd = flatb & 7;
    bx = slot % gridDim.x;
    by = (slot / gridDim.x) * 8 + xcd;
}

// ---------------------------------------------------------------------------
// fp32 VALU conv (conv1..conv3), PT=4, round-8 FMA chains (bit-identical ->
// sort indices preserved). WPE = min waves/EU: OT=32 -> acc128 -> WPE=2
// (WPE=3 spills, round-10: 1.4GB scratch writes); OT=16 -> acc64 (~125 regs)
// -> WPE=3 for latency coverage (round-11: 2 waves/SIMD left VALUBusy at 49%).
// OT=16/PT=4 keeps 16 FMA per ds_read_b128 and 64 FMA per X-load (round-9's
// PT=2 halved those ratios and regressed). o-fastest staging: 0 conflicts
// (verified round 10/11; at OT=16 bank=(16c+o)%32 covers 32 banks 2-way).
// ---------------------------------------------------------------------------
template<int CIN, int OT, int MODE, bool STATS, int WPE>
__global__ __launch_bounds__(256, WPE) void conv_k(
    const float* __restrict__ X, const float* __restrict__ W,
    const float* __restrict__ insc, const float* __restrict__ insh,
    float* __restrict__ Y, float* __restrict__ ssum, float* __restrict__ ssq,
    int COUT)
{
    constexpr int PT = 4;
    constexpr int NT = 256 * PT;               // 1024 points per block
    constexpr int CC = (CIN < 128) ? CIN : 128;
    __shared__ __align__(16) float Ws[CC][OT];
    __shared__ float lsum[OT];
    __shared__ float lsq[OT];

    int bx, by;
    xcd_swz(bx, by);
    const int tid = threadIdx.x;
    const int b = (by * NT) / NPTS;
    const int n = (by * NT) % NPTS + tid * PT;
    const int obase = bx * OT;

    if (STATS) {
        for (int i = tid; i < OT; i += 256) { lsum[i] = 0.f; lsq[i] = 0.f; }
    }

    float acc[OT][PT];
#pragma unroll
    for (int o = 0; o < OT; ++o)
#pragma unroll
        for (int p = 0; p < PT; ++p) acc[o][p] = 0.f;

    const float* Xb = X + (size_t)b * CIN * NPTS;

    for (int c0 = 0; c0 < CIN; c0 += CC) {
        // o-fastest staging: conflict-free LDS writes; W is L1/L2-resident.
        for (int i = tid; i < CC * OT; i += 256) {
            int o = i % OT, c = i / OT;
            int oo = obase + o;
            Ws[c][o] = (oo < COUT) ? W[(size_t)oo * CIN + (c0 + c)] : 0.f;
        }
        __syncthreads();
#pragma unroll 2
        for (int c = 0; c < CC; ++c) {
            const int cx = c0 + c;
            float xv[PT];
            float4 t = *(const float4*)(Xb + (size_t)cx * NPTS + n);
            xv[0] = t.x; xv[1] = t.y; xv[2] = t.z; xv[3] = t.w;
            if (MODE == 1) {
                float s = insc[cx], h = insh[cx];
#pragma unroll
                for (int p = 0; p < PT; ++p)
                    xv[p] = fmaxf(fmaf(xv[p], s, h), 0.f);
            }
            const float4* wrow = (const float4*)(&Ws[c][0]);
#pragma unroll
            for (int o4 = 0; o4 < OT / 4; ++o4) {
                float4 w = wrow[o4];
#pragma unroll
                for (int p = 0; p < PT; ++p) {
                    acc[o4 * 4 + 0][p] = fmaf(w.x, xv[p], acc[o4 * 4 + 0][p]);
                    acc[o4 * 4 + 1][p] = fmaf(w.y, xv[p], acc[o4 * 4 + 1][p]);
                    acc[o4 * 4 + 2][p] = fmaf(w.z, xv[p], acc[o4 * 4 + 2][p]);
                    acc[o4 * 4 + 3][p] = fmaf(w.w, xv[p], acc[o4 * 4 + 3][p]);
                }
            }
        }
        __syncthreads();
    }

#pragma unroll
    for (int o = 0; o < OT; ++o) {
        const int oo = obase + o;
        if (oo < COUT) {
            float v[PT];
#pragma unroll
            for (int p = 0; p < PT; ++p) v[p] = acc[o][p];
            *(float4*)(Y + ((size_t)b * COUT + oo) * NPTS + n) =
                make_float4(v[0], v[1], v[2], v[3]);
            if (STATS) {
                float s = (v[0] + v[1]) + (v[2] + v[3]);
                float q = fmaf(v[0], v[0], fmaf(v[1], v[1], fmaf(v[2], v[2], v[3] * v[3])));
#pragma unroll
                for (int d = 32; d >= 1; d >>= 1) {
                    s += __shfl_xor(s, d, 64);
                    q += __shfl_xor(q, d, 64);
                }
                if ((tid & 63) == 0) {
                    atomicAdd(&lsum[o], s);
                    atomicAdd(&lsq[o], q);
                }
            }
        }
    }
    if (STATS) {
        __syncthreads();
        for (int i = tid; i < OT; i += 256) {
            int oo = obase + i;
            if (oo < COUT) {
                atomicAdd(&ssum[oo], lsum[i]);
                atomicAdd(&ssq[oo], lsq[i]);
            }
        }
    }
}

// per-channel BN fold: scale = g/sqrt(var+eps), shift = be - mean*scale
__global__ void bnstats_k(const float* __restrict__ ssum, const float* __restrict__ ssq,
                          const float* __restrict__ g, const float* __restrict__ be,
                          float* __restrict__ scale, float* __restrict__ shift, int C)
{
    int c = blockIdx.x * blockDim.x + threadIdx.x;
    if (c >= C) return;
    const float inv = 1.0f / (float)BNTOT;
    float m = ssum[c] * inv;
    float var = fmaf(ssq[c], inv, -m * m);
    float sc = g[c] / sqrtf(var + 1e-5f);
    scale[c] = sc;
    shift[c] = fmaf(-m, sc, be[c]);
}

// SoftPool (UNCHANGED): stable 16-smallest per (b,k), then gather-dot.
__global__ __launch_bounds__(256) void softpool_k(
    const float* __restrict__ y3, const float* __restrict__ sc3,
    const float* __restrict__ sh3, const float* __restrict__ w9,
    const float* __restrict__ b9, float* __restrict__ vout)
{
    extern __shared__ float vals[];
    __shared__ int sidx[NP];
    __shared__ float wv[4];
    __shared__ int wi[4];
    __shared__ float ps[4];

    const int tid = threadIdx.x;
    const int b = blockIdx.x >> 5;
    const int k = blockIdx.x & 31;

    const float* src = y3 + ((size_t)b * 32 + k) * NPTS;
    const float sck = sc3[k], shk = sh3[k];
    for (int i = tid; i < NPTS; i += 256) vals[i] = fmaf(src[i], sck, shk);
    __syncthreads();

    for (int p = 0; p < NP; ++p) {
        float bv = INFINITY;
        int bi = 0x7fffffff;
        for (int i = tid; i < NPTS; i += 256) {
            float x = vals[i];
            if (x < bv) { bv = x; bi = i; }
        }
#pragma unroll
        for (int d = 32; d >= 1; d >>= 1) {
            float ov = __shfl_xor(bv, d, 64);
            int oi = __shfl_xor(bi, d, 64);
            if (ov < bv || (ov == bv && oi < bi)) { bv = ov; bi = oi; }
        }
        if ((tid & 63) == 0) { wv[tid >> 6] = bv; wi[tid >> 6] = bi; }
        __syncthreads();
        if (tid == 0) {
            for (int w = 1; w < 4; ++w)
                if (wv[w] < bv || (wv[w] == bv && wi[w] < bi)) { bv = wv[w]; bi = wi[w]; }
            sidx[p] = bi;
            vals[bi] = INFINITY;
        }
        __syncthreads();
    }

    float part = 0.f;
    for (int i = tid; i < 32 * NP; i += 256) {
        int c = i >> 4, p = i & 15;
        float h = fmaf(y3[((size_t)b * 32 + c) * NPTS + sidx[p]], sc3[c], sh3[c]);
        part += w9[c * NP + p] * h;
    }
#pragma unroll
    for (int d = 32; d >= 1; d >>= 1) part += __shfl_xor(part, d, 64);
    if ((tid & 63) == 0) ps[tid >> 6] = part;
    __syncthreads();
    if (tid == 0) vout[b * 32 + k] = ps[0] + ps[1] + ps[2] + ps[3] + b9[0];
}

// h1T[b][n][64] fp16 = relu(bn1(y1)), LDS transpose; S1b per-(b,c) sums.
__global__ __launch_bounds__(256) void transformT_k(
    const float* __restrict__ y1, const float* __restrict__ sc,
    const float* __restrict__ sh, f16* __restrict__ h1T, float* __restrict__ S1b)
{
    __shared__ float arr[64][65];
    __shared__ float s1loc[64];
    const int tid = threadIdx.x;
    const int b = blockIdx.x >> 8;
    const int n0 = (blockIdx.x & 255) * 64;
    if (tid < 64) s1loc[tid] = 0.f;

    const int c = tid >> 2, j4 = tid & 3;
    const float scv = sc[c], shv = sh[c];
    const float* src = y1 + ((size_t)b * 64 + c) * NPTS + n0 + j4 * 16;
    float ls = 0.f;
#pragma unroll
    for (int j = 0; j < 4; ++j) {
        float4 v = *(const float4*)(src + j * 4);
        float r0 = fmaxf(fmaf(v.x, scv, shv), 0.f);
        float r1 = fmaxf(fmaf(v.y, scv, shv), 0.f);
        float r2 = fmaxf(fmaf(v.z, scv, shv), 0.f);
        float r3 = fmaxf(fmaf(v.w, scv, shv), 0.f);
        arr[j4 * 16 + j * 4 + 0][c] = r0;
        arr[j4 * 16 + j * 4 + 1][c] = r1;
        arr[j4 * 16 + j * 4 + 2][c] = r2;
        arr[j4 * 16 + j * 4 + 3][c] = r3;
        ls += (r0 + r1) + (r2 + r3);
    }
    ls += __shfl_xor(ls, 1, 64);
    ls += __shfl_xor(ls, 2, 64);
    if (j4 == 0) atomicAdd(&s1loc[c], ls);
    __syncthreads();

    const int n = tid >> 2, cj = (tid & 3) * 16;
    f16x8 h0, h1v;
#pragma unroll
    for (int jj = 0; jj < 8; ++jj) h0[jj] = (f16)arr[n][cj + jj];
#pragma unroll
    for (int jj = 0; jj < 8; ++jj) h1v[jj] = (f16)arr[n][cj + 8 + jj];
    f16* dst = h1T + ((size_t)b * NPTS + n0 + n) * 64 + cj;
    *(f16x8*)(dst) = h0;
    *(f16x8*)(dst + 8) = h1v;

    if (tid < 64) atomicAdd(&S1b[b * 64 + tid], s1loc[tid]);
}

// MFMA SYRK (UNCHANGED): M[i][j] = sum_r H[r][i]*H[r][j] over h1T.
__global__ __launch_bounds__(256, 2) void msyrk_k(const f16* __restrict__ h1T,
                                                  float* __restrict__ M)
{
    __shared__ float Mlds[4][4096];
    const int tid = threadIdx.x;
    const int lane = tid & 63;
    const int llo = lane & 15, lhi = lane >> 4;
    const int wv = tid >> 6;
    const int gw = blockIdx.x * 4 + wv;
    constexpr int SPW = (BNTOT / 32) / 2048;

    f32x4 acc[4][4];
#pragma unroll
    for (int ti = 0; ti < 4; ++ti)
#pragma unroll
        for (int tj = 0; tj < 4; ++tj) acc[ti][tj] = (f32x4){0.f, 0.f, 0.f, 0.f};

#pragma unroll
    for (int s = 0; s < SPW; ++s) {
        const size_t r0 = (size_t)gw * (SPW * 32) + (size_t)s * 32 + 8 * lhi;
        const f16* base = h1T + r0 * 64 + llo;
        f16x8 f[4];
#pragma unroll
        for (int t = 0; t < 4; ++t)
#pragma unroll
            for (int i = 0; i < 8; ++i)
                f[t][i] = base[(size_t)i * 64 + t * 16];
#pragma unroll
        for (int ti = 0; ti < 4; ++ti)
#pragma unroll
            for (int tj = 0; tj < 4; ++tj)
                acc[ti][tj] = __builtin_amdgcn_mfma_f32_16x16x32_f16(
                    f[ti], f[tj], acc[ti][tj], 0, 0, 0);
    }

#pragma unroll
    for (int ti = 0; ti < 4; ++ti)
#pragma unroll
        for (int tj = 0; tj < 4; ++tj)
#pragma unroll
            for (int r = 0; r < 4; ++r)
                Mlds[wv][(ti * 16 + 4 * lhi + r) * 64 + tj * 16 + llo] = acc[ti][tj][r];
    __syncthreads();
    for (int i = tid; i < 4096; i += 256)
        atomicAdd(&M[i], (Mlds[0][i] + Mlds[1][i]) + (Mlds[2][i] + Mlds[3][i]));
}

// BN4 from input moments; emits per-(b,o) fused shift.
__global__ void bnstats45_k(const float* __restrict__ w4, const float* __restrict__ vv,
                            const float* __restrict__ S1b, const float* __restrict__ M,
                            const float* __restrict__ g, const float* __restrict__ be,
                            float* __restrict__ sc4, float* __restrict__ shift4b)
{
    __shared__ float vvL[512], sbL[1024], ML[4096];
    const int tid = threadIdx.x;
    for (int i = tid; i < 512; i += 512) vvL[i] = vv[i];
    for (int i = tid; i < 1024; i += 512) sbL[i] = S1b[i];
    for (int i = tid; i < 4096; i += 512) ML[i] = M[i];
    __syncthreads();
    const int o = tid;
    float wg[32], wh[64];
#pragma unroll
    for (int i = 0; i < 32; ++i) wg[i] = w4[o * 96 + i];
#pragma unroll
    for (int j = 0; j < 64; ++j) wh[j] = w4[o * 96 + 32 + j];
    float gbv[16];
    float sumy = 0.f, sumsq = 0.f;
#pragma unroll
    for (int b = 0; b < 16; ++b) {
        float gb = 0.f, hb = 0.f;
#pragma unroll
        for (int i = 0; i < 32; ++i) gb = fmaf(wg[i], vvL[b * 32 + i], gb);
#pragma unroll
        for (int j = 0; j < 64; ++j) hb = fmaf(wh[j], sbL[b * 64 + j], hb);
        gbv[b] = gb;
        sumy += (float)NPTS * gb + hb;
        sumsq += (float)NPTS * gb * gb + 2.f * gb * hb;
    }
    for (int j = 0; j < 64; ++j) {
        float t = 0.f;
#pragma unroll
        for (int j2 = 0; j2 < 64; ++j2) t = fmaf(ML[j * 64 + j2], wh[j2], t);
        sumsq = fmaf(wh[j], t, sumsq);
    }
    const float inv = 1.0f / (float)BNTOT;
    float m = sumy * inv;
    float var = fmaf(sumsq, inv, -m * m);
    float s = g[o] / sqrtf(var + 1e-5f);
    float sh4v = fmaf(-m, s, be[o]);
    sc4[o] = s;
#pragma unroll
    for (int b = 0; b < 16; ++b)
        shift4b[b * 512 + o] = fmaf(gbv[b], s, sh4v);
}

// fp32 -> fp16 weight conversion (optionally a column slice of src)
__global__ void wcvt_k(const float* __restrict__ src, f16* __restrict__ dst,
                       int rows, int cols, int srcStride, int srcOff)
{
    int i = blockIdx.x * 256 + threadIdx.x;
    if (i < rows * cols) {
        int r = i / cols, c = i % cols;
        dst[i] = (f16)src[(size_t)r * srcStride + srcOff + c];
    }
}

// ---------------------------------------------------------------------------
// LDS-tiled MFMA GEMM (round-7 structure + XCD swizzle). UNCHANGED.
// ---------------------------------------------------------------------------
#define GLOAD(KT, RA, RB)                                                       \
  {                                                                             \
    const int kb_ = (KT) * 64 + sj * 8;                                         \
    float4 is0, is1, ih0, ih1;                                                  \
    if (INAFF) {                                                                \
      is0 = *(const float4*)(insc + kb_); is1 = *(const float4*)(insc + kb_ + 4); \
      ih0 = *(const float4*)(insh + kb_); ih1 = *(const float4*)(insh + kb_ + 4); \
    }                                                                           \
    _Pragma("unroll")                                                           \
    for (int i_ = 0; i_ < 4; ++i_) {                                            \
      const int r_ = sr + i_ * 32;                                              \
      RA[i_] = *(const f16x8*)(wsrc + (size_t)r_ * K + kb_);                    \
      f16x8 xb = *(const f16x8*)(xsrc + (size_t)r_ * K + kb_);                  \
      if (INAFF) {                                                              \
        f16x8 nb;                                                               \
        nb[0] = (f16)fmaxf(fmaf((float)xb[0], is0.x, ih0.x), 0.f);              \
        nb[1] = (f16)fmaxf(fmaf((float)xb[1], is0.y, ih0.y), 0.f);              \
        nb[2] = (f16)fmaxf(fmaf((float)xb[2], is0.z, ih0.z), 0.f);              \
        nb[3] = (f16)fmaxf(fmaf((float)xb[3], is0.w, ih0.w), 0.f);              \
        nb[4] = (f16)fmaxf(fmaf((float)xb[4], is1.x, ih1.x), 0.f);              \
        nb[5] = (f16)fmaxf(fmaf((float)xb[5], is1.y, ih1.y), 0.f);              \
        nb[6] = (f16)fmaxf(fmaf((float)xb[6], is1.z, ih1.z), 0.f);              \
        nb[7] = (f16)fmaxf(fmaf((float)xb[7], is1.w, ih1.w), 0.f);              \
        xb = nb;                                                                \
      }                                                                         \
      RB[i_] = xb;                                                              \
    }                                                                           \
  }

#define DSWRITE(RA, RB)                                                         \
  {                                                                             \
    _Pragma("unroll")                                                           \
    for (int i_ = 0; i_ < 4; ++i_) {                                            \
      const int r_ = sr + i_ * 32;                                              \
      const int sw_ = sj ^ (r_ & 7);                                            \
      *(f16x8*)(&As[r_ * 64 + sw_ * 8]) = RA[i_];                               \
      *(f16x8*)(&Bs[r_ * 64 + sw_ * 8]) = RB[i_];                               \
    }                                                                           \
  }

template<int KS, bool INAFF, bool OUTAFF, bool STATS>
__global__ __launch_bounds__(256, 2) void gconv_k(
    const f16* __restrict__ Xt, const f16* __restrict__ Wh,
    const float* __restrict__ insc, const float* __restrict__ insh,
    const float* __restrict__ outsc, const float* __restrict__ outshB,
    f16* __restrict__ Y, float* __restrict__ ssum, float* __restrict__ ssq,
    const int M)
{
    constexpr int K = KS * 64;
    __shared__ __align__(16) f16 As[128 * 64];
    __shared__ __align__(16) f16 Bs[128 * 64];
    __shared__ float lsum[128];
    __shared__ float lsq[128];

    int bx, by;
    xcd_swz(bx, by);
    const int tid = threadIdx.x;
    const int w = tid >> 6, lane = tid & 63;
    const int llo = lane & 15, lhi = lane >> 4;
    const int wn = w >> 1, wm = w & 1;
    const int n0 = by * 128;
    const int m0 = bx * 128;
    const int sr = tid >> 3, sj = tid & 7;

    if (STATS && tid < 128) { lsum[tid] = 0.f; lsq[tid] = 0.f; }

    const f16* xsrc = Xt + (size_t)n0 * K;
    const f16* wsrc = Wh + (size_t)m0 * K;

    f32x4 acc[4][4];
#pragma unroll
    for (int nf = 0; nf < 4; ++nf)
#pragma unroll
        for (int mf = 0; mf < 4; ++mf) acc[nf][mf] = (f32x4){0.f, 0.f, 0.f, 0.f};

    f16x8 ra0[4], rb0[4], ra1[4], rb1[4];
    GLOAD(0, ra0, rb0);

#pragma unroll
    for (int kt = 0; kt < KS; ++kt) {
        if ((kt & 1) == 0) { DSWRITE(ra0, rb0); } else { DSWRITE(ra1, rb1); }
        __syncthreads();
        if (kt + 1 < KS) {
            if ((kt & 1) == 0) { GLOAD(kt + 1, ra1, rb1); }
            else               { GLOAD(kt + 1, ra0, rb0); }
        }
#pragma unroll
        for (int ks = 0; ks < 2; ++ks) {
            f16x8 af[4], bf[4];
#pragma unroll
            for (int f = 0; f < 4; ++f) {
                const int ml = wm * 64 + f * 16 + llo;
                af[f] = *(const f16x8*)(&As[ml * 64 + ((ks * 4 + lhi) ^ (ml & 7)) * 8]);
                const int nl = wn * 64 + f * 16 + llo;
                bf[f] = *(const f16x8*)(&Bs[nl * 64 + ((ks * 4 + lhi) ^ (nl & 7)) * 8]);
            }
#pragma unroll
            for (int nf = 0; nf < 4; ++nf)
#pragma unroll
                for (int mf = 0; mf < 4; ++mf)
                    acc[nf][mf] = __builtin_amdgcn_mfma_f32_16x16x32_f16(
                        af[mf], bf[nf], acc[nf][mf], 0, 0, 0);
        }
        __syncthreads();
    }

    const int bl = n0 / NPTS;
#pragma unroll
    for (int nf = 0; nf < 4; ++nf) {
        const int n = n0 + wn * 64 + nf * 16 + llo;
        f16* row = Y + (size_t)n * M + m0 + wm * 64;
#pragma unroll
        for (int mf = 0; mf < 4; ++mf) {
            const int moff = mf * 16 + 4 * lhi;
            float v0 = acc[nf][mf][0], v1 = acc[nf][mf][1];
            float v2 = acc[nf][mf][2], v3 = acc[nf][mf][3];
            if (OUTAFF) {
                const int mg = m0 + wm * 64 + moff;
                float4 s = *(const float4*)(outsc + mg);
                float4 h = *(const float4*)(outshB + (size_t)bl * M + mg);
                v0 = fmaxf(fmaf(v0, s.x, h.x), 0.f);
                v1 = fmaxf(fmaf(v1, s.y, h.y), 0.f);
                v2 = fmaxf(fmaf(v2, s.z, h.z), 0.f);
                v3 = fmaxf(fmaf(v3, s.w, h.w), 0.f);
            }
            F16x4 o;
            o.v[0] = (f16)v0; o.v[1] = (f16)v1; o.v[2] = (f16)v2; o.v[3] = (f16)v3;
            *(F16x4*)(row + moff) = o;
        }
    }
    if (STATS) {
#pragma unroll
        for (int mf = 0; mf < 4; ++mf) {
#pragma unroll
            for (int r = 0; r < 4; ++r) {
                float s = acc[0][mf][r] + acc[1][mf][r] + acc[2][mf][r] + acc[3][mf][r];
                float q = fmaf(acc[0][mf][r], acc[0][mf][r],
                          fmaf(acc[1][mf][r], acc[1][mf][r],
                          fmaf(acc[2][mf][r], acc[2][mf][r],
                               acc[3][mf][r] * acc[3][mf][r])));
#pragma unroll
                for (int d = 1; d < 16; d <<= 1) {
                    s += __shfl_xor(s, d, 64);
                    q += __shfl_xor(q, d, 64);
                }
                if (llo == 0) {
                    atomicAdd(&lsum[wm * 64 + mf * 16 + 4 * lhi + r], s);
                    atomicAdd(&lsq [wm * 64 + mf * 16 + 4 * lhi + r], q);
                }
            }
        }
        __syncthreads();
        if (tid < 128) {
            atomicAdd(&ssum[m0 + tid], lsum[tid]);
            atomicAdd(&ssq [m0 + tid], lsq [tid]);
        }
    }
}

// conv7: out[b][o][n] = tanh(b7 + sum_c w7[o][c]*relu(bn6(y6T[n][c])))
__global__ __launch_bounds__(256) void conv7T_k(
    const f16* __restrict__ y6T, const float* __restrict__ sc6,
    const float* __restrict__ sh6, const float* __restrict__ w7,
    const float* __restrict__ b7, float* __restrict__ out)
{
    __shared__ float wsc[128], wsh[128], ww[384];
    const int tid = threadIdx.x;
    if (tid < 128) { wsc[tid] = sc6[tid]; wsh[tid] = sh6[tid]; }
    for (int i = tid; i < 384; i += 256) ww[i] = w7[i];
    __syncthreads();
    const int gid = blockIdx.x * 256 + tid;
    const int b = gid >> 14, nl = gid & 16383;
    const f16* row = y6T + (size_t)gid * 128;
    float a0 = 0.f, a1 = 0.f, a2 = 0.f;
    for (int c8 = 0; c8 < 128; c8 += 8) {
        f16x8 v8 = *(const f16x8*)(row + c8);
#pragma unroll
        for (int j = 0; j < 8; ++j) {
            float hv = fmaxf(fmaf((float)v8[j], wsc[c8 + j], wsh[c8 + j]), 0.f);
            a0 = fmaf(ww[c8 + j], hv, a0);
            a1 = fmaf(ww[128 + c8 + j], hv, a1);
            a2 = fmaf(ww[256 + c8 + j], hv, a2);
        }
    }
    const float bv = b7[0];
    out[((size_t)b * 3 + 0) * NPTS + nl] = tanhf(a0 + bv);
    out[((size_t)b * 3 + 1) * NPTS + nl] = tanhf(a1 + bv);
    out[((size_t)b * 3 + 2) * NPTS + nl] = tanhf(a2 + bv);
}

// Diagnostic fallback
__global__ void fill_k(float* __restrict__ out, int nsize, float val)
{
    int i = blockIdx.x * 256 + threadIdx.x;
    if (i < nsize) out[i] = val;
}

extern "C" void kernel_launch(void* const* d_in, const int* in_sizes, int n_in,
                              void* d_out, int out_size, void* d_ws, size_t ws_size,
                              hipStream_t stream)
{
    const float* x   = (const float*)d_in[0];
    const float* w1  = (const float*)d_in[1];
    const float* g1  = (const float*)d_in[3];
    const float* be1 = (const float*)d_in[4];
    const float* w2  = (const float*)d_in[5];
    const float* g2  = (const float*)d_in[7];
    const float* be2 = (const float*)d_in[8];
    const float* w3  = (const float*)d_in[9];
    const float* g3  = (const float*)d_in[11];
    const float* be3 = (const float*)d_in[12];
    const float* w9  = (const float*)d_in[13];
    const float* b9  = (const float*)d_in[14];
    const float* w4  = (const float*)d_in[15];
    const float* g4  = (const float*)d_in[17];
    const float* be4 = (const float*)d_in[18];
    const float* w5  = (const float*)d_in[19];
    const float* g5  = (const float*)d_in[21];
    const float* be5 = (const float*)d_in[22];
    const float* w6  = (const float*)d_in[23];
    const float* g6  = (const float*)d_in[25];
    const float* be6 = (const float*)d_in[26];
    const float* w7  = (const float*)d_in[27];
    const float* b7  = (const float*)d_in[28];
    float* out = (float*)d_out;

    // ---- workspace plan (226 MiB), lifetime-aliased (unchanged) ----
    const size_t MB = 1048576u;
    const size_t need = 226 * MB;
    if (ws_size < need) {
        float val = 1000.0f + (float)(ws_size >> 20);
        fill_k<<<(out_size + 255) / 256, 256, 0, stream>>>(out, out_size, val);
        return;
    }

    char* base = (char*)d_ws;
    float* y1  = (float*)(base + 1 * MB);
    f16*   y4T = (f16*)(base + 1 * MB);
    f16*   y6T = (f16*)(base + 1 * MB);
    float* y2  = (float*)(base + 65 * MB);
    f16*   h1T = (f16*)(base + 65 * MB);
    f16*   y5T = (f16*)(base + 97 * MB);
    float* y3  = (float*)(base + 193 * MB);
    float* sm  = (float*)(base + 225 * MB);
    f16*   w5h = (f16*)(base + 225 * MB + 131072);
    f16*   w6h = w5h + 131072;   // 256*512
    f16*   w4hh = w6h + 32768;   // 128*256; w4hh is 512*64

    float* sum1 = sm + 0,     *sq1 = sm + 512,  *sc1 = sm + 1024, *sh1 = sm + 1536;
    float* sum2 = sm + 2048,  *sq2 = sm + 2560, *sc2 = sm + 3072, *sh2 = sm + 3584;
    float* sum3 = sm + 4096,  *sq3 = sm + 4608, *sc3 = sm + 5120, *sh3 = sm + 5632;
    float* sc4  = sm + 6144;
    float* sum5 = sm + 7168,  *sq5 = sm + 7680, *sc5 = sm + 8192, *sh5 = sm + 8704;
    float* sum6 = sm + 9216,  *sq6 = sm + 9728, *sc6 = sm + 10240,*sh6 = sm + 10752;
    float* vv   = sm + 11264;            // 512
    float* S1b  = sm + 11776;            // 1024
    float* Mh   = sm + 12800;            // 4096
    float* shift4b = sm + 16896;         // 16*512 -> end 25088

    hipMemsetAsync(sm, 0, 16896 * sizeof(float), stream);

    const dim3 blk(256);
    const int tiles4 = BNTOT / 1024;     // 256 n-tiles (PT=4)

    // fp16 weight copies
    wcvt_k<<<(256 * 512 + 255) / 256, blk, 0, stream>>>(w5, w5h, 256, 512, 512, 0);
    wcvt_k<<<(128 * 256 + 255) / 256, blk, 0, stream>>>(w6, w6h, 128, 256, 256, 0);
    wcvt_k<<<(512 * 64 + 255) / 256, blk, 0, stream>>>(w4, w4hh, 512, 64, 96, 32);

    // conv1..conv3 (fp32; per-element FMA chains identical to round 8)
    conv_k<4, 32, 0, true, 2><<<dim3(2, tiles4), blk, 0, stream>>>(
        x, w1, nullptr, nullptr, y1, sum1, sq1, 64);
    bnstats_k<<<1, 256, 0, stream>>>(sum1, sq1, g1, be1, sc1, sh1, 64);

    // conv2: OT=16 (acc 64 regs) + 3 waves/EU for latency coverage
    conv_k<64, 16, 1, true, 3><<<dim3(8, tiles4), blk, 0, stream>>>(
        y1, w2, sc1, sh1, y2, sum2, sq2, 128);
    bnstats_k<<<1, 256, 0, stream>>>(sum2, sq2, g2, be2, sc2, sh2, 128);

    conv_k<128, 16, 1, true, 3><<<dim3(2, tiles4), blk, 0, stream>>>(
        y2, w3, sc2, sh2, y3, sum3, sq3, 32);
    bnstats_k<<<1, 256, 0, stream>>>(sum3, sq3, g3, be3, sc3, sh3, 32);

    softpool_k<<<512, blk, NPTS * sizeof(float), stream>>>(y3, sc3, sh3, w9, b9, vv);

    // h1T + S1b, MFMA SYRK moment, BN4 (fused per-(b,o) shift)
    transformT_k<<<16 * 256, blk, 0, stream>>>(y1, sc1, sh1, h1T, S1b);
    msyrk_k<<<512, blk, 0, stream>>>(h1T, Mh);
    bnstats45_k<<<1, 512, 0, stream>>>(w4, vv, S1b, Mh, g4, be4, sc4, shift4b);

    // conv4+conv5 in 4 batch-chunks (tiled MFMA GEMM); y4T bounce in y1 region
    for (int q = 0; q < 4; ++q) {
        const f16* h1q = h1T + (size_t)q * 4 * NPTS * 64;
        f16* y5q = y5T + (size_t)q * 4 * NPTS * 256;
        gconv_k<1, false, true, false><<<dim3(4, 512), blk, 0, stream>>>(
            h1q, w4hh, nullptr, nullptr, sc4, shift4b + (size_t)q * 4 * 512,
            y4T, nullptr, nullptr, 512);
        gconv_k<8, false, false, true><<<dim3(2, 512), blk, 0, stream>>>(
            y4T, w5h, nullptr, nullptr, nullptr, nullptr,
            y5q, sum5, sq5, 256);
    }
    bnstats_k<<<1, 256, 0, stream>>>(sum5, sq5, g5, be5, sc5, sh5, 256);

    // conv6: K=256 -> M=128, INAFF(bn5+relu at staging), raw + stats
    gconv_k<4, true, false, true><<<dim3(1, 2048), blk, 0, stream>>>(
        y5T, w6h, sc5, sh5, nullptr, nullptr,
        y6T, sum6, sq6, 128);
    bnstats_k<<<1, 256, 0, stream>>>(sum6, sq6, g6, be6, sc6, sh6, 128);

    // conv7: VALU, bn6+relu on load, tanh out
    conv7T_k<<<BNTOT / 256, blk, 0, stream>>>(y6T, sc6, sh6, w7, b7, out);
}